// Round 2
// baseline (393.935 us; speedup 1.0000x reference)
//
#include <hip/hip_runtime.h>

typedef unsigned short ushort_t;
typedef __attribute__((ext_vector_type(8))) short short8;
typedef __attribute__((ext_vector_type(4))) float f32x4;
typedef __attribute__((ext_vector_type(4))) int int4v;

#define RNUM 8
#define FDIM 128

__device__ __forceinline__ float bf2f(ushort_t u) {
    union { unsigned int i; float f; } x;
    x.i = ((unsigned int)u) << 16;
    return x.f;
}
__device__ __forceinline__ ushort_t f2bf(float f) {
    union { float f; unsigned int i; } x;
    x.f = f;
    unsigned int u = x.i;
    u += 0x7fffu + ((u >> 16) & 1u);   // round-to-nearest-even
    return (ushort_t)(u >> 16);
}

// async global->LDS, 16B per lane; LDS side must be wave-contiguous
__device__ __forceinline__ void gl_lds16(const void* g, void* s) {
    __builtin_amdgcn_global_load_lds(
        (const __attribute__((address_space(1))) unsigned int*)g,
        (__attribute__((address_space(3))) unsigned int*)s, 16, 0, 0);
}

// ---------------- linked-list segment index ----------------
// head[seg] -> most recent edge id; meta[i] = (src[i], prev edge with same seg).
// One 8B load per chain hop (halves meta request count vs separate esrc/nxt).

__global__ void init_head(int* __restrict__ head, int n) {
    int i = blockIdx.x * 256 + threadIdx.x;
    if (i < n) head[i] = -1;
}

__global__ void link_kernel(const int* __restrict__ src, const int* __restrict__ dst,
                            const int* __restrict__ et,
                            int* head, int2* __restrict__ meta, int E) {
    int i = blockIdx.x * 256 + threadIdx.x;
    if (i < E) {
        int seg = dst[i] * RNUM + et[i];
        int prev = atomicExch(&head[seg], i);
        meta[i] = make_int2(src[i], prev);
    }
}

// ------- weight transpose + bf16 cast: Wt[r][h][f] = bf16(W[r][f][h]), r=8 -> root -------

__global__ __launch_bounds__(256) void transpose_w(const float* __restrict__ rel_w,
                                                   const float* __restrict__ root_w,
                                                   ushort_t* __restrict__ Wt) {
    int r = blockIdx.x;  // 0..8
    const float* src = (r < 8) ? (rel_w + r * 16384) : root_w;
    __shared__ ushort_t t[128 * 130];
    for (int idx = threadIdx.x; idx < 16384; idx += 256)
        t[(idx >> 7) * 130 + (idx & 127)] = f2bf(src[idx]);
    __syncthreads();
    ushort_t* d = Wt + r * 16384;
    for (int idx = threadIdx.x; idx < 16384; idx += 256)
        d[idx] = t[(idx & 127) * 130 + (idx >> 7)];
}

// ---------------- cast x (f32) into compact bf16 buffer (pad rows zeroed) ----------------

__global__ void cast_x(const float* __restrict__ x, ushort_t* __restrict__ xc,
                       int total, int totalPad) {
    int i = (blockIdx.x * 256 + threadIdx.x) * 8;
    if (i >= totalPad) return;
    ushort_t o[8];
    if (i < total) {
        float4 v0 = *(const float4*)(x + i);
        float4 v1 = *(const float4*)(x + i + 4);
        o[0] = f2bf(v0.x); o[1] = f2bf(v0.y); o[2] = f2bf(v0.z); o[3] = f2bf(v0.w);
        o[4] = f2bf(v1.x); o[5] = f2bf(v1.y); o[6] = f2bf(v1.z); o[7] = f2bf(v1.w);
    } else {
#pragma unroll
        for (int k = 0; k < 8; ++k) o[k] = 0;
    }
    *(int4v*)(xc + i) = *(int4v*)o;
}

// ---------------- fused layer: per-slot segment means -> LDS A-tile -> MFMA ----------------
// Block = 128 nodes, 512 threads (8 waves). For r<8, the block computes the 128
// per-(node,r) means on the fly: quarter-wave qw walks 4 chains interleaved,
// gathering rows (16 lanes x 16B = 256B) from the compact feature buffer X,
// then writes the bf16 mean into the XOR-swizzled LDS A-tile. Slot 8 stages
// X rows directly (root term). Eliminates the 100MB mean write + 100MB re-read
// per layer that seg_mean + rgcn_gemm paid.

template <bool FINAL>
__global__ __launch_bounds__(512, 4) void rgcn_fused(
    const int* __restrict__ head, const int2* __restrict__ meta,
    const ushort_t* __restrict__ X,    // [NPAD][128] bf16, compact
    const ushort_t* __restrict__ Wt,   // [9][128][128] bf16 (h-major)
    const float* __restrict__ bias,
    float* __restrict__ outF, ushort_t* __restrict__ Xout, int N) {
    __shared__ ushort_t As[128 * 128];
    __shared__ ushort_t Bs[128 * 128];
    __shared__ int headL[128 * RNUM];
    int tid = threadIdx.x;
    int wv = tid >> 6, lane = tid & 63;
    int l16 = lane & 15, q = lane >> 4;
    int qw = tid >> 4;                 // 0..31: quarter-wave id
    int nodeBase = blockIdx.x * 128;

    // stage this block's 1024 head entries (consecutive ints; pad nodes -> -1)
    for (int i = tid; i < 128 * RNUM; i += 512)
        headL[i] = (nodeBase + (i >> 3) < N) ? head[nodeBase * RNUM + i] : -1;

    f32x4 acc[8];
#pragma unroll
    for (int ct = 0; ct < 8; ++ct) acc[ct] = (f32x4){0.f, 0.f, 0.f, 0.f};

    __syncthreads();   // headL ready

    for (int r = 0; r < 9; ++r) {
        if (r > 0) __syncthreads();    // WAR: previous slot's LDS reads done
        if (r < 8) {
            // ---- phase A: 32 qw x 4 rows, chains interleaved ----
            int row0 = qw * 4;
            float av[4][8];
            int ccnt[4], cj[4], cs[4], cn[4];
#pragma unroll
            for (int c = 0; c < 4; ++c) {
                ccnt[c] = 0;
#pragma unroll
                for (int k = 0; k < 8; ++k) av[c][k] = 0.f;
                cj[c] = headL[(row0 + c) * RNUM + r];
            }
#pragma unroll
            for (int c = 0; c < 4; ++c)
                if (cj[c] >= 0) { int2 m = meta[cj[c]]; cs[c] = m.x; cn[c] = m.y; }
            // loop while ANY chain active (AND of ids has sign bit clear)
            while ((cj[0] & cj[1] & cj[2] & cj[3]) >= 0) {
                int4v v[4];
#pragma unroll
                for (int c = 0; c < 4; ++c)
                    if (cj[c] >= 0) v[c] = *(const int4v*)(X + (size_t)cs[c] * FDIM + l16 * 8);
                int2 m2[4];
#pragma unroll
                for (int c = 0; c < 4; ++c)
                    if (cj[c] >= 0 && cn[c] >= 0) m2[c] = meta[cn[c]];
#pragma unroll
                for (int c = 0; c < 4; ++c) {
                    if (cj[c] >= 0) {
                        const ushort_t* p = (const ushort_t*)&v[c];
#pragma unroll
                        for (int k = 0; k < 8; ++k) av[c][k] += bf2f(p[k]);
                        ++ccnt[c];
                        cj[c] = cn[c];
                        cs[c] = m2[c].x;
                        cn[c] = m2[c].y;
                    }
                }
            }
            // write means into swizzled A-tile: chunk l16 of row -> pos l16^(row&15)
#pragma unroll
            for (int c = 0; c < 4; ++c) {
                int row = row0 + c;
                float sc = (ccnt[c] > 0) ? 1.0f / (float)ccnt[c] : 0.f;
                ushort_t ov[8];
#pragma unroll
                for (int k = 0; k < 8; ++k) ov[k] = f2bf(av[c][k] * sc);
                *(int4v*)((char*)As + row * 256 + ((l16 ^ (row & 15)) * 16)) = *(int4v*)ov;
            }
        } else {
            // ---- slot 8: stage X rows (root term) ----
#pragma unroll
            for (int i = 0; i < 4; ++i) {
                int L = i * 512 + tid;
                int row = L >> 4;
                int c = (L & 15) ^ (row & 15);
                gl_lds16(X + (size_t)(nodeBase + row) * FDIM + c * 8,
                         (char*)As + (size_t)L * 16);
            }
        }
        // ---- stage B (weights; L2-resident) ----
#pragma unroll
        for (int i = 0; i < 4; ++i) {
            int L = i * 512 + tid;
            int row = L >> 4;
            int c = (L & 15) ^ (row & 15);
            gl_lds16(Wt + r * 16384 + row * 128 + c * 8, (char*)Bs + (size_t)L * 16);
        }
        __syncthreads();   // drains vmcnt; ds_writes visible
        // ---- MFMA: wave wv owns rows wv*16..wv*16+15 ----
#pragma unroll
        for (int s = 0; s < 4; ++s) {
            int pos = ((s * 4 + q) ^ l16) * 16;
            short8 a = *(const short8*)((const char*)As + (wv * 16 + l16) * 256 + pos);
#pragma unroll
            for (int ct = 0; ct < 8; ++ct) {
                short8 b = *(const short8*)((const char*)Bs + (ct * 16 + l16) * 256 + pos);
                acc[ct] = __builtin_amdgcn_mfma_f32_16x16x32_bf16(a, b, acc[ct], 0, 0, 0);
            }
        }
    }

    // epilogue: C layout col = lane&15, row = q*4 + reg (within wave's 16-row tile)
#pragma unroll
    for (int ct = 0; ct < 8; ++ct) {
        int h = ct * 16 + l16;
        float bv = bias[h];
#pragma unroll
        for (int reg = 0; reg < 4; ++reg) {
            int node = nodeBase + wv * 16 + q * 4 + reg;
            float v = acc[ct][reg] + bv;
            if (FINAL) {
                if (node < N) outF[(size_t)node * FDIM + h] = v;
            } else {
                Xout[(size_t)node * FDIM + h] = f2bf(fmaxf(v, 0.f));  // pad rows: defined (A=0)
            }
        }
    }
}

__global__ void copy_emb(const float* __restrict__ e, float* __restrict__ out, int n) {
    int i = blockIdx.x * 256 + threadIdx.x;
    if (i < n) out[i] = e[i];
}

// ---------------- launch ----------------

extern "C" void kernel_launch(void* const* d_in, const int* in_sizes, int n_in,
                              void* d_out, int out_size, void* d_ws, size_t ws_size,
                              hipStream_t stream) {
    const float* x        = (const float*)d_in[0];
    const int* edge_index = (const int*)d_in[1];
    const int* edge_type  = (const int*)d_in[2];
    const float* rel_w0   = (const float*)d_in[3];
    const float* root_w0  = (const float*)d_in[4];
    const float* bias0    = (const float*)d_in[5];
    const float* rel_w1   = (const float*)d_in[6];
    const float* root_w1  = (const float*)d_in[7];
    const float* bias1    = (const float*)d_in[8];
    const float* rel_emb  = (const float*)d_in[9];

    int N = in_sizes[0] / FDIM;   // 50000
    int E = in_sizes[1] / 2;      // 800000
    int NSEG = N * RNUM;          // 400000
    const int* src = edge_index;
    const int* dst = edge_index + E;

    int nb_gemm = (N + 127) / 128;      // 391
    int NPAD = nb_gemm * 128;           // 50048

    char* w = (char*)d_ws;
    auto alloc = [&](size_t bytes) -> char* {
        char* p = w;
        w += (bytes + 255) & ~(size_t)255;
        return p;
    };
    int* head     = (int*)alloc((size_t)NSEG * 4);
    int2* meta    = (int2*)alloc((size_t)E * 8);
    ushort_t* Wt  = (ushort_t*)alloc((size_t)2 * 9 * 16384 * 2);
    ushort_t* xc  = (ushort_t*)alloc((size_t)NPAD * FDIM * 2);   // 12.8 MB compact bf16 x
    ushort_t* h1c = (ushort_t*)alloc((size_t)NPAD * FDIM * 2);   // 12.8 MB compact bf16 relu(h1)
    (void)ws_size; (void)n_in; (void)out_size;

    int nb_seg  = (NSEG + 255) / 256;
    int nb_E    = (E + 255) / 256;
    int nb_cast = (NPAD * FDIM) / (256 * 8);   // 3128

    init_head<<<nb_seg, 256, 0, stream>>>(head, NSEG);
    link_kernel<<<nb_E, 256, 0, stream>>>(src, dst, edge_type, head, meta, E);
    transpose_w<<<9, 256, 0, stream>>>(rel_w0, root_w0, Wt);
    transpose_w<<<9, 256, 0, stream>>>(rel_w1, root_w1, Wt + 9 * 16384);
    cast_x<<<nb_cast, 256, 0, stream>>>(x, xc, N * FDIM, NPAD * FDIM);

    rgcn_fused<false><<<nb_gemm, 512, 0, stream>>>(head, meta, xc, Wt, bias0,
                                                   nullptr, h1c, N);
    rgcn_fused<true><<<nb_gemm, 512, 0, stream>>>(head, meta, h1c, Wt + 9 * 16384, bias1,
                                                  (float*)d_out, nullptr, N);
    copy_emb<<<4, 256, 0, stream>>>(rel_emb, (float*)d_out + (size_t)N * FDIM,
                                    in_sizes[9]);
}

// Round 3
// 323.949 us; speedup vs baseline: 1.2160x; 1.2160x over previous
//
#include <hip/hip_runtime.h>

typedef unsigned short ushort_t;
typedef __attribute__((ext_vector_type(8))) short short8;
typedef __attribute__((ext_vector_type(4))) float f32x4;
typedef __attribute__((ext_vector_type(4))) int int4v;

#define RNUM 8
#define FDIM 128
#define KDIM 1152   // 9 * 128: slots 0..7 = per-relation means, slot 8 = x / relu(h)

__device__ __forceinline__ float bf2f(ushort_t u) {
    union { unsigned int i; float f; } x;
    x.i = ((unsigned int)u) << 16;
    return x.f;
}
__device__ __forceinline__ ushort_t f2bf(float f) {
    union { float f; unsigned int i; } x;
    x.f = f;
    unsigned int u = x.i;
    u += 0x7fffu + ((u >> 16) & 1u);   // round-to-nearest-even
    return (ushort_t)(u >> 16);
}

// async global->LDS, 16B per lane; LDS side must be wave-contiguous
__device__ __forceinline__ void gl_lds16(const void* g, void* s) {
    __builtin_amdgcn_global_load_lds(
        (const __attribute__((address_space(1))) unsigned int*)g,
        (__attribute__((address_space(3))) unsigned int*)s, 16, 0, 0);
}

// ---------------- multi-head linked-list segment index ----------------
// 4 interleaved lists per segment: head4[seg*4+k], k = edge_id & 3.
// meta[i] = (src[i], prev edge in same (seg,k) list). Cuts pointer-chase
// depth from ~2-3 to ~1 and gives each quarter-wave 4 independent gathers
// in flight while keeping round-0's grid/occupancy (1 segment per qw).

__global__ void init_head(int* __restrict__ head, int n) {
    int i = blockIdx.x * 256 + threadIdx.x;
    if (i < n) head[i] = -1;
}

__global__ void link_kernel(const int* __restrict__ src, const int* __restrict__ dst,
                            const int* __restrict__ et,
                            int* head, int2* __restrict__ meta, int E) {
    int i = blockIdx.x * 256 + threadIdx.x;
    if (i < E) {
        int seg = dst[i] * RNUM + et[i];
        int prev = atomicExch(&head[seg * 4 + (i & 3)], i);
        meta[i] = make_int2(src[i], prev);
    }
}

// ------- weight transpose + bf16 cast: Wt[r][h][f] = bf16(W[r][f][h]), r=8 -> root -------

__global__ __launch_bounds__(256) void transpose_w(const float* __restrict__ rel_w,
                                                   const float* __restrict__ root_w,
                                                   ushort_t* __restrict__ Wt) {
    int r = blockIdx.x;  // 0..8
    const float* src = (r < 8) ? (rel_w + r * 16384) : root_w;
    __shared__ ushort_t t[128 * 130];
    for (int idx = threadIdx.x; idx < 16384; idx += 256)
        t[(idx >> 7) * 130 + (idx & 127)] = f2bf(src[idx]);
    __syncthreads();
    ushort_t* d = Wt + r * 16384;
    for (int idx = threadIdx.x; idx < 16384; idx += 256)
        d[idx] = t[(idx & 127) * 130 + (idx >> 7)];
}

// ---------------- cast x (f32) into Mx slot 8 ----------------

__global__ void cast_x(const float* __restrict__ x, ushort_t* __restrict__ Mx, int total) {
    int i = (blockIdx.x * 256 + threadIdx.x) * 8;
    if (i >= total) return;
    float4 v0 = *(const float4*)(x + i);
    float4 v1 = *(const float4*)(x + i + 4);
    ushort_t o[8] = {f2bf(v0.x), f2bf(v0.y), f2bf(v0.z), f2bf(v0.w),
                     f2bf(v1.x), f2bf(v1.y), f2bf(v1.z), f2bf(v1.w)};
    int row = i >> 7, col = i & 127;
    *(int4v*)(Mx + (size_t)row * KDIM + 1024 + col) = *(int4v*)o;
}

// ---------------- phase A: per-(node,rel) segment means ----------------
// One quarter-wave (16 lanes x 16B) per segment (round-0 grid), walking the
// segment's 4 sub-chains interleaved. All 4 sums fold into one accumulator.

__global__ __launch_bounds__(256) void seg_mean(const int4v* __restrict__ head4,
                                                const int2* __restrict__ meta,
                                                ushort_t* Mx, int NSEG) {
    int t = blockIdx.x * 256 + threadIdx.x;
    int seg = t >> 4;
    int l16 = t & 15;
    if (seg >= NSEG) return;
    const ushort_t* gbase = Mx + 1024 + (size_t)l16 * 8;

    float acc[8];
#pragma unroll
    for (int k = 0; k < 8; ++k) acc[k] = 0.f;

    int4v h4 = head4[seg];           // 4 sub-chain heads in one 16B load
    int j[4], s[4], n[4];
#pragma unroll
    for (int c = 0; c < 4; ++c) j[c] = h4[c];
#pragma unroll
    for (int c = 0; c < 4; ++c)
        if (j[c] >= 0) { int2 m = meta[j[c]]; s[c] = m.x; n[c] = m.y; }

    int cnt = 0;
    // loop while ANY sub-chain active: AND of ids has sign bit set iff all == -1
    while ((j[0] & j[1] & j[2] & j[3]) >= 0) {
        int4v v[4];
#pragma unroll
        for (int c = 0; c < 4; ++c)
            if (j[c] >= 0) v[c] = *(const int4v*)(gbase + (size_t)s[c] * KDIM);
        int2 m2[4];
#pragma unroll
        for (int c = 0; c < 4; ++c)
            if (j[c] >= 0 && n[c] >= 0) m2[c] = meta[n[c]];
#pragma unroll
        for (int c = 0; c < 4; ++c) {
            if (j[c] >= 0) {
                const ushort_t* p = (const ushort_t*)&v[c];
#pragma unroll
                for (int k = 0; k < 8; ++k) acc[k] += bf2f(p[k]);
                ++cnt;
                j[c] = n[c];
                s[c] = m2[c].x;
                n[c] = m2[c].y;
            }
        }
    }

    float sc = (cnt > 0) ? 1.0f / (float)cnt : 0.f;
    ushort_t ov[8];
#pragma unroll
    for (int k = 0; k < 8; ++k) ov[k] = f2bf(acc[k] * sc);
    *(int4v*)(Mx + (size_t)(seg >> 3) * KDIM + (seg & 7) * 128 + l16 * 8) = *(int4v*)ov;
}

// ---------------- phase B: dense GEMM  C[128n x 128h] = Mx[128n x 1152k] @ Wt^T ----------
// A,B staged per r-slot via global_load_lds (16B) into XOR-swizzled contiguous LDS.
// LDS chunk layout: 16B chunk c of row n stored at position c ^ (n & 15).

template <bool FINAL>
__global__ __launch_bounds__(256) void rgcn_gemm(
    const ushort_t* Mx, const ushort_t* __restrict__ Wt,
    const float* __restrict__ bias, float* __restrict__ outF,
    ushort_t* MxOut, int N) {
    __shared__ ushort_t As[128 * 128];
    __shared__ ushort_t Bs[128 * 128];
    int tid = threadIdx.x;
    int wid = tid >> 6, lane = tid & 63;
    int l16 = lane & 15, q = lane >> 4;
    int nodeBase = blockIdx.x * 128;

    f32x4 acc[2][8];
#pragma unroll
    for (int rt = 0; rt < 2; ++rt)
#pragma unroll
        for (int ct = 0; ct < 8; ++ct) acc[rt][ct] = (f32x4){0.f, 0.f, 0.f, 0.f};

    for (int r = 0; r < 9; ++r) {
        __syncthreads();  // previous iteration's LDS reads done
#pragma unroll
        for (int i = 0; i < 8; ++i) {
            int L = i * 256 + tid;          // 16B slot index, wave-contiguous
            int row = L >> 4;               // 0..127
            int c = (L & 15) ^ (row & 15);  // logical chunk for this slot
            gl_lds16(Mx + (size_t)(nodeBase + row) * KDIM + r * 128 + c * 8,
                     (char*)As + (size_t)L * 16);
            gl_lds16(Wt + r * 16384 + row * 128 + c * 8,
                     (char*)Bs + (size_t)L * 16);
        }
        __syncthreads();  // drains vmcnt -> staged data visible
#pragma unroll
        for (int s = 0; s < 4; ++s) {
            int pos = ((s * 4 + q) ^ l16) * 16;
            short8 a0 = *(const short8*)((const char*)As + ((2 * wid + 0) * 16 + l16) * 256 + pos);
            short8 a1 = *(const short8*)((const char*)As + ((2 * wid + 1) * 16 + l16) * 256 + pos);
#pragma unroll
            for (int ct = 0; ct < 8; ++ct) {
                short8 b = *(const short8*)((const char*)Bs + (ct * 16 + l16) * 256 + pos);
                acc[0][ct] = __builtin_amdgcn_mfma_f32_16x16x32_bf16(a0, b, acc[0][ct], 0, 0, 0);
                acc[1][ct] = __builtin_amdgcn_mfma_f32_16x16x32_bf16(a1, b, acc[1][ct], 0, 0, 0);
            }
        }
    }
    // epilogue: C layout col = lane&15, row = q*4 + reg
#pragma unroll
    for (int rt = 0; rt < 2; ++rt) {
#pragma unroll
        for (int ct = 0; ct < 8; ++ct) {
            int h = ct * 16 + l16;
            float bv = bias[h];
#pragma unroll
            for (int reg = 0; reg < 4; ++reg) {
                int node = nodeBase + (2 * wid + rt) * 16 + q * 4 + reg;
                if (node < N) {
                    float v = acc[rt][ct][reg] + bv;
                    if (FINAL) {
                        outF[(size_t)node * FDIM + h] = v;
                    } else {
                        v = fmaxf(v, 0.f);
                        MxOut[(size_t)node * KDIM + 1024 + h] = f2bf(v);
                    }
                }
            }
        }
    }
}

__global__ void copy_emb(const float* __restrict__ e, float* __restrict__ out, int n) {
    int i = blockIdx.x * 256 + threadIdx.x;
    if (i < n) out[i] = e[i];
}

// ---------------- launch ----------------

extern "C" void kernel_launch(void* const* d_in, const int* in_sizes, int n_in,
                              void* d_out, int out_size, void* d_ws, size_t ws_size,
                              hipStream_t stream) {
    const float* x        = (const float*)d_in[0];
    const int* edge_index = (const int*)d_in[1];
    const int* edge_type  = (const int*)d_in[2];
    const float* rel_w0   = (const float*)d_in[3];
    const float* root_w0  = (const float*)d_in[4];
    const float* bias0    = (const float*)d_in[5];
    const float* rel_w1   = (const float*)d_in[6];
    const float* root_w1  = (const float*)d_in[7];
    const float* bias1    = (const float*)d_in[8];
    const float* rel_emb  = (const float*)d_in[9];

    int N = in_sizes[0] / FDIM;   // 50000
    int E = in_sizes[1] / 2;      // 800000
    int NSEG = N * RNUM;          // 400000
    const int* src = edge_index;
    const int* dst = edge_index + E;

    int nb_gemm = (N + 127) / 128;      // 391
    int NPAD = nb_gemm * 128;           // 50048 (staging reads padded rows)

    char* w = (char*)d_ws;
    auto alloc = [&](size_t bytes) -> char* {
        char* p = w;
        w += (bytes + 255) & ~(size_t)255;
        return p;
    };
    int* head    = (int*)alloc((size_t)NSEG * 4 * 4);   // 4 sub-lists per segment
    int2* meta   = (int2*)alloc((size_t)E * 8);
    ushort_t* Wt = (ushort_t*)alloc((size_t)2 * 9 * 16384 * 2);
    ushort_t* Mx = (ushort_t*)alloc((size_t)NPAD * KDIM * 2);   // ~115 MB
    (void)ws_size; (void)n_in; (void)out_size;

    int nb_head = (NSEG * 4 + 255) / 256;
    int nb_E    = (E + 255) / 256;
    int nb_mean = (NSEG * 16) / 256;        // 25000
    int nb_cast = (N * FDIM) / (256 * 8);   // 3125

    init_head<<<nb_head, 256, 0, stream>>>(head, NSEG * 4);
    link_kernel<<<nb_E, 256, 0, stream>>>(src, dst, edge_type, head, meta, E);
    transpose_w<<<9, 256, 0, stream>>>(rel_w0, root_w0, Wt);
    transpose_w<<<9, 256, 0, stream>>>(rel_w1, root_w1, Wt + 9 * 16384);
    cast_x<<<nb_cast, 256, 0, stream>>>(x, Mx, N * FDIM);

    seg_mean<<<nb_mean, 256, 0, stream>>>((const int4v*)head, meta, Mx, NSEG);
    rgcn_gemm<false><<<nb_gemm, 256, 0, stream>>>(Mx, Wt, bias0, nullptr, Mx, N);
    seg_mean<<<nb_mean, 256, 0, stream>>>((const int4v*)head, meta, Mx, NSEG);
    rgcn_gemm<true><<<nb_gemm, 256, 0, stream>>>(Mx, Wt + 9 * 16384, bias1,
                                                 (float*)d_out, nullptr, N);
    copy_emb<<<4, 256, 0, stream>>>(rel_emb, (float*)d_out + (size_t)N * FDIM,
                                    in_sizes[9]);
}